// Round 2
// baseline (229.600 us; speedup 1.0000x reference)
//
#include <hip/hip_runtime.h>
#include <hip/hip_bf16.h>

// z = x[B,D] . W[O,D]^T + bias[O]; out = z*z.  B=131072, D=128, O=256. fp32 I/O.
// R2 strategy: NO LDS, NO barriers. Each wave holds its 64-col slice of W as
// persistent bf16 MFMA B-fragments in registers (64 VGPR), loaded once per
// block. Block = 4 waves = 4 col-quarters; loop over 16-row x tiles.
// Memory-bound target ~32us (67 MB read + 134 MB write @ 6.3 TB/s).

#define B_ROWS 131072
#define D_DIM  128
#define O_DIM  256
#define THREADS 256
#define NBLOCKS 2048
#define ROWS_PER_BLOCK 64     // 4 tiles of 16 rows
#define TILES (ROWS_PER_BLOCK / 16)

using bf16x8 = __attribute__((ext_vector_type(8))) short;  // 8 bf16 (4 VGPRs)
using f32x4  = __attribute__((ext_vector_type(4))) float;

__device__ __forceinline__ short bf16rne(float f) {
    unsigned u = __builtin_bit_cast(unsigned, f);
    u += 0x7FFFu + ((u >> 16) & 1u);        // round-to-nearest-even (finite inputs)
    return (short)(u >> 16);
}

__device__ __forceinline__ bf16x8 pack8(float4 h0, float4 h1) {
    bf16x8 t;
    t[0] = bf16rne(h0.x); t[1] = bf16rne(h0.y);
    t[2] = bf16rne(h0.z); t[3] = bf16rne(h0.w);
    t[4] = bf16rne(h1.x); t[5] = bf16rne(h1.y);
    t[6] = bf16rne(h1.z); t[7] = bf16rne(h1.w);
    return t;
}

__global__ __launch_bounds__(THREADS, 3)   // 3 waves/EU -> VGPR cap ~168; est ~150
void hyper_linear_sq_kernel(const float* __restrict__ x,
                            const float* __restrict__ weight,
                            const float* __restrict__ bias,
                            float* __restrict__ out) {
    const int lane  = threadIdx.x & 63;
    const int wid   = threadIdx.x >> 6;    // 0..3 -> column quarter
    const int n16   = lane & 15;
    const int quad  = lane >> 4;
    const int cbase = wid * 64;

    // ---- Persistent B fragments: bfrag[ct][ks][j] = W[cbase+ct*16+n16][ks*32+quad*8+j]
    bf16x8 bfrag[4][4];
    #pragma unroll
    for (int ct = 0; ct < 4; ++ct) {
        const float* wr = weight + (cbase + ct * 16 + n16) * D_DIM + quad * 8;
        #pragma unroll
        for (int ks = 0; ks < 4; ++ks) {
            float4 h0 = *(const float4*)(wr + ks * 32);
            float4 h1 = *(const float4*)(wr + ks * 32 + 4);
            bfrag[ct][ks] = pack8(h0, h1);
        }
    }

    // ---- Bias for this lane's 4 output columns
    float bv[4];
    #pragma unroll
    for (int ct = 0; ct < 4; ++ct) bv[ct] = bias[cbase + ct * 16 + n16];

    const int rowbase0 = blockIdx.x * ROWS_PER_BLOCK;

    for (int t = 0; t < TILES; ++t) {
        const int rowbase = rowbase0 + t * 16;

        // A fragments: a[ks][j] = x[rowbase+n16][ks*32+quad*8+j]
        const float* xr = x + (rowbase + n16) * D_DIM + quad * 8;
        bf16x8 a[4];
        #pragma unroll
        for (int ks = 0; ks < 4; ++ks) {
            float4 h0 = *(const float4*)(xr + ks * 32);
            float4 h1 = *(const float4*)(xr + ks * 32 + 4);
            a[ks] = pack8(h0, h1);
        }

        f32x4 acc[4];
        #pragma unroll
        for (int ct = 0; ct < 4; ++ct) acc[ct] = (f32x4){0.f, 0.f, 0.f, 0.f};

        #pragma unroll
        for (int ks = 0; ks < 4; ++ks) {
            #pragma unroll
            for (int ct = 0; ct < 4; ++ct) {
                acc[ct] = __builtin_amdgcn_mfma_f32_16x16x32_bf16(a[ks], bfrag[ct][ks], acc[ct], 0, 0, 0);
            }
        }

        // Epilogue: C[row=quad*4+r][col=ct*16+n16] ; z = acc + bias ; out = z*z
        #pragma unroll
        for (int ct = 0; ct < 4; ++ct) {
            const int col = cbase + ct * 16 + n16;
            #pragma unroll
            for (int r = 0; r < 4; ++r) {
                const int row = rowbase + quad * 4 + r;
                float z = acc[ct][r] + bv[ct];
                out[row * O_DIM + col] = z * z;
            }
        }
    }
}

extern "C" void kernel_launch(void* const* d_in, const int* in_sizes, int n_in,
                              void* d_out, int out_size, void* d_ws, size_t ws_size,
                              hipStream_t stream) {
    const float* x    = (const float*)d_in[0];
    const float* w    = (const float*)d_in[1];
    const float* bias = (const float*)d_in[2];
    float* out        = (float*)d_out;
    hipLaunchKernelGGL(hyper_linear_sq_kernel, dim3(NBLOCKS), dim3(THREADS), 0, stream,
                       x, w, bias, out);
}

// Round 4
// 225.449 us; speedup vs baseline: 1.0184x; 1.0184x over previous
//
#include <hip/hip_runtime.h>
#include <hip/hip_bf16.h>

// z = x[B,D] . W[O,D]^T + bias[O]; out = z*z.  B=131072, D=128, O=256. fp32 I/O.
// R4 = R3 with compile fix: nontemporal store through ext_vector f32x4
// (clang builtin rejects HIP_vector_type). Register-resident W frags per wave,
// wave-local LDS-transposed epilogue (dwordx4 stores, no __syncthreads),
// x prefetch one tile ahead.

#define B_ROWS 131072
#define D_DIM  128
#define O_DIM  256
#define THREADS 256
#define NBLOCKS 2048
#define TILES 4
#define ROWS_PER_BLOCK (TILES * 16)   // 64
#define LDS_PITCH 68                  // dwords: 64 + 4 pad -> <=2-way banks, 16B-aligned rows

using bf16x8 = __attribute__((ext_vector_type(8))) short;  // 8 bf16 (4 VGPRs)
using f32x4  = __attribute__((ext_vector_type(4))) float;

__device__ __forceinline__ short bf16rne(float f) {
    unsigned u = __builtin_bit_cast(unsigned, f);
    u += 0x7FFFu + ((u >> 16) & 1u);        // round-to-nearest-even (finite inputs)
    return (short)(u >> 16);
}

__device__ __forceinline__ bf16x8 pack8(float4 h0, float4 h1) {
    bf16x8 t;
    t[0] = bf16rne(h0.x); t[1] = bf16rne(h0.y);
    t[2] = bf16rne(h0.z); t[3] = bf16rne(h0.w);
    t[4] = bf16rne(h1.x); t[5] = bf16rne(h1.y);
    t[6] = bf16rne(h1.z); t[7] = bf16rne(h1.w);
    return t;
}

__global__ __launch_bounds__(THREADS, 3)
void hyper_linear_sq_kernel(const float* __restrict__ x,
                            const float* __restrict__ weight,
                            const float* __restrict__ bias,
                            float* __restrict__ out) {
    // per-wave 16x64 f32 transpose tile, pitch 68 dwords (4352 B/wave, 17408 B total)
    __shared__ float lds[4][16][LDS_PITCH];

    const int lane  = threadIdx.x & 63;
    const int wid   = threadIdx.x >> 6;    // column quarter
    const int n16   = lane & 15;
    const int quad  = lane >> 4;
    const int cbase = wid * 64;

    // ---- Persistent B fragments: bfrag[ct][ks][j] = W[cbase+ct*16+n16][ks*32+quad*8+j]
    bf16x8 bfrag[4][4];
    #pragma unroll
    for (int ct = 0; ct < 4; ++ct) {
        const float* wr = weight + (cbase + ct * 16 + n16) * D_DIM + quad * 8;
        #pragma unroll
        for (int ks = 0; ks < 4; ++ks) {
            float4 h0 = *(const float4*)(wr + ks * 32);
            float4 h1 = *(const float4*)(wr + ks * 32 + 4);
            bfrag[ct][ks] = pack8(h0, h1);
        }
    }

    float bv[4];
    #pragma unroll
    for (int ct = 0; ct < 4; ++ct) bv[ct] = bias[cbase + ct * 16 + n16];

    const int rowbase0 = blockIdx.x * ROWS_PER_BLOCK;
    const float* xbase = x + ((long)rowbase0 + n16) * D_DIM + quad * 8;

    // ---- Preload tile 0's x rows
    float4 raw[8];
    #pragma unroll
    for (int ks = 0; ks < 4; ++ks) {
        raw[2 * ks]     = *(const float4*)(xbase + ks * 32);
        raw[2 * ks + 1] = *(const float4*)(xbase + ks * 32 + 4);
    }

    #pragma unroll
    for (int t = 0; t < TILES; ++t) {
        // pack current tile's A fragments
        bf16x8 a[4];
        #pragma unroll
        for (int ks = 0; ks < 4; ++ks) a[ks] = pack8(raw[2 * ks], raw[2 * ks + 1]);

        // prefetch next tile's x rows before MFMA
        float4 rawn[8];
        if (t + 1 < TILES) {
            const float* xn = xbase + (long)(t + 1) * 16 * D_DIM;
            #pragma unroll
            for (int ks = 0; ks < 4; ++ks) {
                rawn[2 * ks]     = *(const float4*)(xn + ks * 32);
                rawn[2 * ks + 1] = *(const float4*)(xn + ks * 32 + 4);
            }
        }

        f32x4 acc[4];
        #pragma unroll
        for (int ct = 0; ct < 4; ++ct) acc[ct] = (f32x4){0.f, 0.f, 0.f, 0.f};

        #pragma unroll
        for (int ks = 0; ks < 4; ++ks) {
            #pragma unroll
            for (int ct = 0; ct < 4; ++ct) {
                acc[ct] = __builtin_amdgcn_mfma_f32_16x16x32_bf16(a[ks], bfrag[ct][ks], acc[ct], 0, 0, 0);
            }
        }

        // ---- wave-local transposed epilogue (no barrier; same-wave LDS round-trip)
        // C layout: row = quad*4+r, col(in quarter) = ct*16+n16
        #pragma unroll
        for (int ct = 0; ct < 4; ++ct) {
            #pragma unroll
            for (int r = 0; r < 4; ++r) {
                float z = acc[ct][r] + bv[ct];
                lds[wid][quad * 4 + r][ct * 16 + n16] = z * z;
            }
        }
        // read back contiguous: sweep s covers rows s*4+quad, cols n16*4..n16*4+3
        #pragma unroll
        for (int s = 0; s < 4; ++s) {
            f32x4 v = *(const f32x4*)&lds[wid][s * 4 + quad][n16 * 4];
            long row = rowbase0 + t * 16 + s * 4 + quad;
            __builtin_nontemporal_store(v, (f32x4*)(out + row * O_DIM + cbase + n16 * 4));
        }

        if (t + 1 < TILES) {
            #pragma unroll
            for (int i = 0; i < 8; ++i) raw[i] = rawn[i];
        }
    }
}

extern "C" void kernel_launch(void* const* d_in, const int* in_sizes, int n_in,
                              void* d_out, int out_size, void* d_ws, size_t ws_size,
                              hipStream_t stream) {
    const float* x    = (const float*)d_in[0];
    const float* w    = (const float*)d_in[1];
    const float* bias = (const float*)d_in[2];
    float* out        = (float*)d_out;
    hipLaunchKernelGGL(hyper_linear_sq_kernel, dim3(NBLOCKS), dim3(THREADS), 0, stream,
                       x, w, bias, out);
}